// Round 6
// baseline (65.550 us; speedup 1.0000x reference)
//
#include <hip/hip_runtime.h>
#include <hip/hip_bf16.h>

// RoI crop-and-resize (bilinear), fp32.
// input: (N=128, C=256, H=64, W=64) fp32
// rois:  (N, 4) fp32  [x1, y1, x2, y2]   (roi height/width == 30 px exactly)
// out:   (N, C, OH=28, OW=28) fp32
//
// R5: isolate the R4b regression — keep CPB=8 double-buffered pipeline,
// revert nontemporal store to plain float4 store (single-variable A/B vs R4b;
// differs from R3 only by CPB 4->8).
// Traffic floor: 268 MB fetch + 103 MB write = 371 MB  (~59 us @ 6.3 TB/s).

constexpr int Nn = 128;
constexpr int Cc = 256;
constexpr int Hh = 64;
constexpr int Ww = 64;
constexpr int OH = 28;
constexpr int OW = 28;
constexpr int ROWS = 32;       // staged rows per channel (covers roi span)
constexpr int LSTRIDE = 65;    // padded LDS row stride (floats); 65 % 32 == 1
constexpr int CPB = 8;         // channels per block (all share n / roi)

__global__ __launch_bounds__(256) void roi_interp_pipe_kernel(
    const float* __restrict__ in,    // N*C*H*W
    const float* __restrict__ rois,  // N*4
    float* __restrict__ out)         // N*C*OH*OW
{
    __shared__ float lds[2][ROWS * LSTRIDE];   // 2 x 8320 B = 16.6 KB

    const int b0 = blockIdx.x * CPB;   // first (n*C + c) of this block
    const int n  = b0 >> 8;            // C = 256
    const int t  = threadIdx.x;

    const float4 roi = ((const float4*)rois)[n];
    const float bx1 = roi.x, by1 = roi.y, bx2 = roi.z, by2 = roi.w;

    // Row slab start: by1 in [1,32) so floor(by1) in [1,31]; rows
    // ybase..ybase+31 cover floor(by1)..floor(by2)+1.
    const int ylo   = (int)floorf(fminf(fmaxf(by1, 0.0f), (float)(Hh - 1)));
    const int ybase = min(ylo, Hh - ROWS);

    // Divide-free weight steps (assoc change vs reference: ~1 ulp).
    const float dx27 = (bx2 - bx1) * (1.0f / 27.0f);
    const float dy27 = (by2 - by1) * (1.0f / 27.0f);

    const float* __restrict__ imgbase =
        in + (size_t)b0 * (Hh * Ww) + (size_t)ybase * Ww;   // 256B aligned

    // Per-thread LDS staging offsets (thread t owns quads t and t+256).
    const int r0i = t >> 4;            // rows 0..15
    const int r1i = (t + 256) >> 4;    // rows 16..31
    const int xi  = (t & 15) * 4;      // float4 never crosses a row

    // ---- prologue: stage channel 0 ----
    float4 p0 = ((const float4*)imgbase)[t];
    float4 p1 = ((const float4*)imgbase)[t + 256];
    int cur = 0;
    {
        float* d0 = &lds[cur][r0i * LSTRIDE + xi];
        float* d1 = &lds[cur][r1i * LSTRIDE + xi];
        d0[0] = p0.x; d0[1] = p0.y; d0[2] = p0.z; d0[3] = p0.w;
        d1[0] = p1.x; d1[1] = p1.y; d1[2] = p1.z; d1[3] = p1.w;
    }

    for (int cc = 0; cc < CPB; ++cc) {
        // Issue next channel's global loads early (latency hides under compute).
        if (cc + 1 < CPB) {
            const float4* nq = (const float4*)(imgbase + (size_t)(cc + 1) * (Hh * Ww));
            p0 = nq[t];
            p1 = nq[t + 256];
        }

        __syncthreads();   // staged writes to lds[cur] visible to all

        // ---- compute channel cc from lds[cur] ----
        if (t < OH * OW / 4) {             // 196 active threads, 1 quad each
            const int oy  = t / (OW / 4);  // /7
            const int oxb = (t - oy * (OW / 4)) * 4;

            float ysf = by1 + dy27 * (float)oy;
            float y0f = fminf(fmaxf(floorf(ysf), 0.0f), (float)(Hh - 1));
            float wy  = ysf - y0f;
            int   y0r = min((int)y0f - ybase, ROWS - 1);   // >= 0 by construction
            int   y1r = min(y0r + 1, ROWS - 1);
            const float* __restrict__ r0 = &lds[cur][y0r * LSTRIDE];
            const float* __restrict__ r1 = &lds[cur][y1r * LSTRIDE];

            float res[4];
#pragma unroll
            for (int j = 0; j < 4; ++j) {
                int   ox  = oxb + j;
                float xsf = bx1 + dx27 * (float)ox;
                float x0f = fminf(fmaxf(floorf(xsf), 0.0f), (float)(Ww - 1));
                int   x0  = (int)x0f;                       // <= 62 -> x0+1 safe
                float wx  = xsf - x0f;
                float v00 = r0[x0], v01 = r0[x0 + 1];
                float v10 = r1[x0], v11 = r1[x0 + 1];
                float top = v00 + wx * (v01 - v00);
                float bot = v10 + wx * (v11 - v10);
                res[j] = top + wy * (bot - top);
            }

            float* op = out + (size_t)(b0 + cc) * (OH * OW) + t * 4;
            *reinterpret_cast<float4*>(op) =
                make_float4(res[0], res[1], res[2], res[3]);
        }

        // ---- write prefetched channel cc+1 into the other buffer ----
        // Safe: readers of lds[cur^1] (channel cc-1) finished before the
        // barrier at the top of this iteration.
        if (cc + 1 < CPB) {
            const int nb = cur ^ 1;
            float* d0 = &lds[nb][r0i * LSTRIDE + xi];
            float* d1 = &lds[nb][r1i * LSTRIDE + xi];
            d0[0] = p0.x; d0[1] = p0.y; d0[2] = p0.z; d0[3] = p0.w;
            d1[0] = p1.x; d1[1] = p1.y; d1[2] = p1.z; d1[3] = p1.w;
            cur = nb;
        }
    }
}

extern "C" void kernel_launch(void* const* d_in, const int* in_sizes, int n_in,
                              void* d_out, int out_size, void* d_ws, size_t ws_size,
                              hipStream_t stream) {
    const float* in   = (const float*)d_in[0];
    const float* rois = (const float*)d_in[1];
    float* out = (float*)d_out;

    const int grid = (Nn * Cc) / CPB;   // 4096 blocks
    roi_interp_pipe_kernel<<<grid, 256, 0, stream>>>(in, rois, out);
}

// Round 7
// 62.982 us; speedup vs baseline: 1.0408x; 1.0408x over previous
//
#include <hip/hip_runtime.h>
#include <hip/hip_bf16.h>

// RoI crop-and-resize (bilinear), fp32.
// input: (N=128, C=256, H=64, W=64) fp32
// rois:  (N, 4) fp32  [x1, y1, x2, y2]   (roi height/width == 30 px exactly)
// out:   (N, C, OH=28, OW=28) fp32
//
// R6 = revert to R3 (best measured: 63.0 us). CPB=4 double-buffered channel
// pipeline; CPB=8 A/B'd at +2.5 us (tail quantization), nt-stores neutral.
// Traffic floor: 268 MB fetch + 103 MB write = 371 MB (~59 us @ 6.3 TB/s);
// this kernel runs at ~5.9 TB/s effective — within ~7% of the mixed ceiling.

constexpr int Nn = 128;
constexpr int Cc = 256;
constexpr int Hh = 64;
constexpr int Ww = 64;
constexpr int OH = 28;
constexpr int OW = 28;
constexpr int ROWS = 32;       // staged rows per channel (covers roi span)
constexpr int LSTRIDE = 65;    // padded LDS row stride (floats); 65 % 32 == 1
constexpr int CPB = 4;         // channels per block (all share n / roi)

__global__ __launch_bounds__(256) void roi_interp_pipe_kernel(
    const float* __restrict__ in,    // N*C*H*W
    const float* __restrict__ rois,  // N*4
    float* __restrict__ out)         // N*C*OH*OW
{
    __shared__ float lds[2][ROWS * LSTRIDE];   // 2 x 8320 B = 16.6 KB

    const int b0 = blockIdx.x * CPB;   // first (n*C + c) of this block
    const int n  = b0 >> 8;            // C = 256
    const int t  = threadIdx.x;

    const float4 roi = ((const float4*)rois)[n];
    const float bx1 = roi.x, by1 = roi.y, bx2 = roi.z, by2 = roi.w;

    // Row slab start: by1 in [1,32) so floor(by1) in [1,31]; rows
    // ybase..ybase+31 cover floor(by1)..floor(by2)+1.
    const int ylo   = (int)floorf(fminf(fmaxf(by1, 0.0f), (float)(Hh - 1)));
    const int ybase = min(ylo, Hh - ROWS);

    // Divide-free weight steps (assoc change vs reference: ~1 ulp).
    const float dx27 = (bx2 - bx1) * (1.0f / 27.0f);
    const float dy27 = (by2 - by1) * (1.0f / 27.0f);

    const float* __restrict__ imgbase =
        in + (size_t)b0 * (Hh * Ww) + (size_t)ybase * Ww;   // 256B aligned

    // Per-thread LDS staging offsets (thread t owns quads t and t+256).
    const int r0i = t >> 4;            // rows 0..15
    const int r1i = (t + 256) >> 4;    // rows 16..31
    const int xi  = (t & 15) * 4;      // float4 never crosses a row

    // ---- prologue: stage channel 0 ----
    float4 p0 = ((const float4*)imgbase)[t];
    float4 p1 = ((const float4*)imgbase)[t + 256];
    int cur = 0;
    {
        float* d0 = &lds[cur][r0i * LSTRIDE + xi];
        float* d1 = &lds[cur][r1i * LSTRIDE + xi];
        d0[0] = p0.x; d0[1] = p0.y; d0[2] = p0.z; d0[3] = p0.w;
        d1[0] = p1.x; d1[1] = p1.y; d1[2] = p1.z; d1[3] = p1.w;
    }

    for (int cc = 0; cc < CPB; ++cc) {
        // Issue next channel's global loads early (latency hides under compute).
        if (cc + 1 < CPB) {
            const float4* nq = (const float4*)(imgbase + (size_t)(cc + 1) * (Hh * Ww));
            p0 = nq[t];
            p1 = nq[t + 256];
        }

        __syncthreads();   // staged writes to lds[cur] visible to all

        // ---- compute channel cc from lds[cur] ----
        if (t < OH * OW / 4) {             // 196 active threads, 1 quad each
            const int oy  = t / (OW / 4);  // /7
            const int oxb = (t - oy * (OW / 4)) * 4;

            float ysf = by1 + dy27 * (float)oy;
            float y0f = fminf(fmaxf(floorf(ysf), 0.0f), (float)(Hh - 1));
            float wy  = ysf - y0f;
            int   y0r = min((int)y0f - ybase, ROWS - 1);   // >= 0 by construction
            int   y1r = min(y0r + 1, ROWS - 1);
            const float* __restrict__ r0 = &lds[cur][y0r * LSTRIDE];
            const float* __restrict__ r1 = &lds[cur][y1r * LSTRIDE];

            float res[4];
#pragma unroll
            for (int j = 0; j < 4; ++j) {
                int   ox  = oxb + j;
                float xsf = bx1 + dx27 * (float)ox;
                float x0f = fminf(fmaxf(floorf(xsf), 0.0f), (float)(Ww - 1));
                int   x0  = (int)x0f;                       // <= 62 -> x0+1 safe
                float wx  = xsf - x0f;
                float v00 = r0[x0], v01 = r0[x0 + 1];
                float v10 = r1[x0], v11 = r1[x0 + 1];
                float top = v00 + wx * (v01 - v00);
                float bot = v10 + wx * (v11 - v10);
                res[j] = top + wy * (bot - top);
            }

            float* op = out + (size_t)(b0 + cc) * (OH * OW) + t * 4;
            *reinterpret_cast<float4*>(op) =
                make_float4(res[0], res[1], res[2], res[3]);
        }

        // ---- write prefetched channel cc+1 into the other buffer ----
        // Safe: readers of lds[cur^1] (channel cc-1) finished before the
        // barrier at the top of this iteration.
        if (cc + 1 < CPB) {
            const int nb = cur ^ 1;
            float* d0 = &lds[nb][r0i * LSTRIDE + xi];
            float* d1 = &lds[nb][r1i * LSTRIDE + xi];
            d0[0] = p0.x; d0[1] = p0.y; d0[2] = p0.z; d0[3] = p0.w;
            d1[0] = p1.x; d1[1] = p1.y; d1[2] = p1.z; d1[3] = p1.w;
            cur = nb;
        }
    }
}

extern "C" void kernel_launch(void* const* d_in, const int* in_sizes, int n_in,
                              void* d_out, int out_size, void* d_ws, size_t ws_size,
                              hipStream_t stream) {
    const float* in   = (const float*)d_in[0];
    const float* rois = (const float*)d_in[1];
    float* out = (float*)d_out;

    const int grid = (Nn * Cc) / CPB;   // 8192 blocks
    roi_interp_pipe_kernel<<<grid, 256, 0, stream>>>(in, rois, out);
}